// Round 2
// baseline (469.163 us; speedup 1.0000x reference)
//
#include <hip/hip_runtime.h>
#include <hip/hip_bf16.h>

// CrossReferenceAttention: B=8, S=1024, H=768, V=8192 (matrix 8193^2 fp32)
// Pipeline:
//   K0 convert_w:      out_w fp32 -> bf16
//   K1 gather_softmax: P[b,i,j] = softmax_j( mask ? M[id_i,id_j]/sqrt(H) : 0 )  (bf16)
//   K2 transpose_h:    hT[b,d,j] = hidden[b,j,d] (bf16)  -> K-major B operand
//   K3 gemm_nt:        ctx[b,i,d] = sum_j P[i,j] * hT[d,j]      (bf16 out)
//   K4 gemm_nt:        proj[b,i,o] = sum_d ctx[i,d] * Wb[o,d]   (fp32 out)
//   K5 residual_ln:    out = LN(hidden + proj + out_b) * ln_w + ln_b
// (Round 2 resubmission: rounds 0-1 never ran — GPU acquisition timeout.)

namespace {
constexpr int kS = 1024;
constexpr int kH = 768;
constexpr int kV = 8193;
}

typedef __attribute__((ext_vector_type(8))) short short8; // 8 x bf16 (4 VGPRs)
typedef __attribute__((ext_vector_type(4))) float f32x4;  // MFMA accumulator

__device__ __forceinline__ unsigned short f2bf(float f) {
  union { float f; unsigned u; } v; v.f = f;
  unsigned r = v.u + 0x7FFFu + ((v.u >> 16) & 1u); // RNE, no NaN inputs here
  return (unsigned short)(r >> 16);
}

__device__ __forceinline__ void async_lds16(const void* gsrc, void* ldst) {
  // 16B per lane, wave-uniform LDS base + lane*16 (guide m97/m104 semantics)
  __builtin_amdgcn_global_load_lds(
      (const __attribute__((address_space(1))) unsigned int*)gsrc,
      (__attribute__((address_space(3))) unsigned int*)ldst, 16, 0, 0);
}

// ---------------- K0: out_w -> bf16 ----------------
__global__ __launch_bounds__(256) void convert_w(const float* __restrict__ w,
                                                 unsigned short* __restrict__ wb) {
  int i = blockIdx.x * 256 + threadIdx.x;      // one float4 per thread
  float4 v = reinterpret_cast<const float4*>(w)[i];
  ushort4 o;
  o.x = f2bf(v.x); o.y = f2bf(v.y); o.z = f2bf(v.z); o.w = f2bf(v.w);
  reinterpret_cast<ushort4*>(wb)[i] = o;
}

// ---------------- K1: gather + softmax -> P (bf16) ----------------
__global__ __launch_bounds__(256) void gather_softmax(const int* __restrict__ ids,
                                                      const float* __restrict__ Mx,
                                                      unsigned short* __restrict__ P) {
  const int i = blockIdx.x, b = blockIdx.y;
  const int t = threadIdx.x;
  const int sid = ids[b * kS + i];
  const float scale = 0.036084391824351615f; // 1/sqrt(768)
  const float* Mrow = Mx + (long)sid * kV;   // only deref'd when sid > 0
  float e[4];
  float lsum = 0.f;
#pragma unroll
  for (int q = 0; q < 4; ++q) {
    int j = t + q * 256;
    int cj = ids[b * kS + j];
    float v = 1.0f;                           // masked-out => score 0 => exp = 1
    if (sid > 0 && cj > 0) v = __expf(Mrow[cj] * scale);
    e[q] = v; lsum += v;
  }
#pragma unroll
  for (int o = 32; o; o >>= 1) lsum += __shfl_down(lsum, o);
  __shared__ float red[4];
  if ((t & 63) == 0) red[t >> 6] = lsum;
  __syncthreads();
  float denom = red[0] + red[1] + red[2] + red[3];
  float inv = 1.0f / denom;
  unsigned short* Pr = P + ((long)b * kS + i) * kS;
#pragma unroll
  for (int q = 0; q < 4; ++q) Pr[t + q * 256] = f2bf(e[q] * inv);
}

// ---------------- K2: hidden -> hT (bf16, [B][H][S]) ----------------
__global__ __launch_bounds__(256) void transpose_h(const float* __restrict__ hidden,
                                                   unsigned short* __restrict__ hT) {
  __shared__ float tile[32][33];
  const int b = blockIdx.z;
  const int h0 = blockIdx.x * 32;  // H dim
  const int s0 = blockIdx.y * 32;  // S dim
  const int t = threadIdx.x;
  const int c = t & 31, r0 = t >> 5;
  const float* src = hidden + (long)b * kS * kH;
#pragma unroll
  for (int q = 0; q < 4; ++q) {
    int r = r0 + q * 8;
    tile[r][c] = src[(long)(s0 + r) * kH + h0 + c];
  }
  __syncthreads();
  unsigned short* dst = hT + (long)b * kH * kS;
#pragma unroll
  for (int q = 0; q < 4; ++q) {
    int hh = r0 + q * 8;
    dst[(long)(h0 + hh) * kS + s0 + c] = f2bf(tile[c][hh]);
  }
}

// ---------------- K3/K4: NT GEMM, C[m,n] = sum_k A[m,k]*Bt[n,k] ----------------
// Block tile 64(M) x 128(N), BK=32, 4 waves each computing 32x64.
// A,Bt bf16 K-major; staging via global_load_lds width=16, linear LDS.
__global__ __launch_bounds__(256) void gemm_nt(
    const unsigned short* __restrict__ A, long aBatchStride,
    const unsigned short* __restrict__ Bt, long bBatchStride,
    unsigned short* __restrict__ Cb, float* __restrict__ Cf,
    long cBatchStride, int N, int K, int outIsBf16) {
  __shared__ __align__(1024) unsigned short lds[6144]; // A:[0,2048) B:[2048,6144) ushorts
  const int b = blockIdx.z;
  const int bn = blockIdx.x, bm = blockIdx.y;
  const unsigned short* Ab = A + (long)b * aBatchStride;
  const unsigned short* Bb = Bt + (long)b * bBatchStride;
  const int t = threadIdx.x;
  const int w = t >> 6, lane = t & 63;
  const int wr = w >> 1, wc = w & 1;       // wave -> 32x64 sub-tile
  const int lrow = lane & 15, kq = lane >> 4;

  const int r = t >> 2, ch = t & 3;        // staging: thread -> (row, 16B chunk)
  const unsigned short* gA = Ab + (long)(bm * 64 + r) * K + ch * 8;
  const unsigned short* gB0 = Bb + (long)(bn * 128 + r) * K + ch * 8;
  const unsigned short* gB1 = gB0 + (long)64 * K;
  unsigned short* ldsA_dst = &lds[w * 512];          // wave-uniform bases
  unsigned short* ldsB0_dst = &lds[2048 + w * 512];
  unsigned short* ldsB1_dst = &lds[4096 + w * 512];

  f32x4 acc[2][4];
#pragma unroll
  for (int mi = 0; mi < 2; ++mi)
#pragma unroll
    for (int ni = 0; ni < 4; ++ni) acc[mi][ni] = (f32x4){0.f, 0.f, 0.f, 0.f};

  const int nk = K >> 5;
  for (int kt = 0; kt < nk; ++kt) {
    async_lds16(gA, ldsA_dst);
    async_lds16(gB0, ldsB0_dst);
    async_lds16(gB1, ldsB1_dst);
    gA += 32; gB0 += 32; gB1 += 32;
    __syncthreads();                       // compiler drains vmcnt before barrier
    short8 af[2], bfr[4];
#pragma unroll
    for (int mi = 0; mi < 2; ++mi)
      af[mi] = *reinterpret_cast<const short8*>(&lds[(wr * 32 + mi * 16 + lrow) * 32 + kq * 8]);
#pragma unroll
    for (int ni = 0; ni < 4; ++ni)
      bfr[ni] = *reinterpret_cast<const short8*>(&lds[2048 + (wc * 64 + ni * 16 + lrow) * 32 + kq * 8]);
#pragma unroll
    for (int mi = 0; mi < 2; ++mi)
#pragma unroll
      for (int ni = 0; ni < 4; ++ni)
        acc[mi][ni] = __builtin_amdgcn_mfma_f32_16x16x32_bf16(af[mi], bfr[ni], acc[mi][ni], 0, 0, 0);
    __syncthreads();
  }

  // C/D layout: col = lane&15, row = (lane>>4)*4 + reg (verified m89/m91)
  const int row0 = bm * 64 + wr * 32;
  const int col0 = bn * 128 + wc * 64;
#pragma unroll
  for (int mi = 0; mi < 2; ++mi)
#pragma unroll
    for (int ni = 0; ni < 4; ++ni)
#pragma unroll
      for (int rg = 0; rg < 4; ++rg) {
        int row = row0 + mi * 16 + kq * 4 + rg;
        int col = col0 + ni * 16 + lrow;
        long off = (long)b * cBatchStride + (long)row * N + col;
        float v = acc[mi][ni][rg];
        if (outIsBf16) Cb[off] = f2bf(v);
        else Cf[off] = v;
      }
}

// ---------------- K5: out = LN(hidden + proj + out_b) ----------------
__global__ __launch_bounds__(256) void residual_ln(
    const float* __restrict__ hidden, const float* __restrict__ proj,
    const float* __restrict__ ob, const float* __restrict__ lw,
    const float* __restrict__ lb, float* __restrict__ out) {
  const long row = blockIdx.x;
  const float* h = hidden + row * kH;
  const float* p = proj + row * kH;
  const int t = threadIdx.x;
  float x[3];
  float s = 0.f, sq = 0.f;
#pragma unroll
  for (int q = 0; q < 3; ++q) {
    int c = t + q * 256;
    float v = h[c] + p[c] + ob[c];
    x[q] = v; s += v; sq += v * v;
  }
#pragma unroll
  for (int o = 32; o; o >>= 1) { s += __shfl_down(s, o); sq += __shfl_down(sq, o); }
  __shared__ float rs[4], rq[4];
  if ((t & 63) == 0) { rs[t >> 6] = s; rq[t >> 6] = sq; }
  __syncthreads();
  float ts = rs[0] + rs[1] + rs[2] + rs[3];
  float tq = rq[0] + rq[1] + rq[2] + rq[3];
  const float invH = 1.0f / 768.0f;
  float mu = ts * invH;
  float var = tq * invH - mu * mu;
  float rstd = rsqrtf(var + 1e-5f);
#pragma unroll
  for (int q = 0; q < 3; ++q) {
    int c = t + q * 256;
    out[row * kH + c] = (x[q] - mu) * rstd * lw[c] + lb[c];
  }
}

extern "C" void kernel_launch(void* const* d_in, const int* in_sizes, int n_in,
                              void* d_out, int out_size, void* d_ws, size_t ws_size,
                              hipStream_t stream) {
  const float* hidden = (const float*)d_in[0];
  const int* ids      = (const int*)d_in[1];
  const float* Mx     = (const float*)d_in[2];
  const float* out_w  = (const float*)d_in[3];
  const float* out_b  = (const float*)d_in[4];
  const float* ln_w   = (const float*)d_in[5];
  const float* ln_b   = (const float*)d_in[6];
  float* out = (float*)d_out;

  // Workspace layout (43.1 MB peak):
  //   [0, 16.78M)  P   (bf16 8x1024x1024)   -- dead after K3
  //   [16.78M, 29.36M) hT (bf16 8x768x1024) -- dead after K3
  //   [29.36M, 41.94M) ctx (bf16 8x1024x768)
  //   [41.94M, 43.12M) Wb (bf16 768x768)
  //   proj (fp32 8x1024x768, 25.17M) reuses [0, 25.17M) after K3.
  char* ws = (char*)d_ws;
  const long szP = 16777216L, szHT = 12582912L, szCTX = 12582912L;
  unsigned short* P   = (unsigned short*)ws;
  unsigned short* hT  = (unsigned short*)(ws + szP);
  unsigned short* ctx = (unsigned short*)(ws + szP + szHT);
  unsigned short* Wb  = (unsigned short*)(ws + szP + szHT + szCTX);
  float* proj = (float*)ws;

  convert_w<<<576, 256, 0, stream>>>(out_w, Wb);
  gather_softmax<<<dim3(1024, 8), 256, 0, stream>>>(ids, Mx, P);
  transpose_h<<<dim3(24, 32, 8), 256, 0, stream>>>(hidden, hT);
  // ctx[b,i,d] = sum_j P[b,i,j] * hT[b,d,j]
  gemm_nt<<<dim3(6, 16, 8), 256, 0, stream>>>(
      P, (long)kS * kS, hT, (long)kH * kS, ctx, nullptr, (long)kS * kH, kH, kS, 1);
  // proj[b,i,o] = sum_d ctx[b,i,d] * Wb[o,d]   (Wb shared: batch stride 0)
  gemm_nt<<<dim3(6, 16, 8), 256, 0, stream>>>(
      ctx, (long)kS * kH, Wb, 0L, nullptr, proj, (long)kS * kH, kH, kH, 0);
  residual_ln<<<8192, 256, 0, stream>>>(hidden, proj, out_b, ln_w, ln_b, out);
}

// Round 5
// 444.591 us; speedup vs baseline: 1.0553x; 1.0553x over previous
//
#include <hip/hip_runtime.h>
#include <hip/hip_bf16.h>

// CrossReferenceAttention: B=8, S=1024, H=768, V=8192 (matrix 8193^2 fp32, 268MB > L3)
// Round 5 = round 3 resubmission (GPU acquisition timeouts; never ran):
//   K1: stream matrix row coalesced into LDS, gather from LDS (was: scattered HBM gather)
//   K3/K4: m97-structure GEMM (128x128 tile, BK=32, 4 waves x 4x4 acc, global_load_lds x16)
//   K5: float4-vectorized LayerNorm

namespace {
constexpr int kS = 1024;
constexpr int kH = 768;
constexpr int kV = 8193;
}

typedef __attribute__((ext_vector_type(8))) short short8; // 8 x bf16 (4 VGPRs)
typedef __attribute__((ext_vector_type(4))) float f32x4;  // MFMA accumulator

__device__ __forceinline__ unsigned short f2bf(float f) {
  union { float f; unsigned u; } v; v.f = f;
  unsigned r = v.u + 0x7FFFu + ((v.u >> 16) & 1u); // RNE
  return (unsigned short)(r >> 16);
}

__device__ __forceinline__ void async_lds16(const void* gsrc, void* ldst) {
  // 16B per lane; LDS dest must be wave-uniform base + lane*16 (m104)
  __builtin_amdgcn_global_load_lds(
      (const __attribute__((address_space(1))) unsigned int*)gsrc,
      (__attribute__((address_space(3))) unsigned int*)ldst, 16, 0, 0);
}

// ---------------- K0: out_w -> bf16 ----------------
__global__ __launch_bounds__(256) void convert_w(const float* __restrict__ w,
                                                 unsigned short* __restrict__ wb) {
  int i = blockIdx.x * 256 + threadIdx.x;
  float4 v = reinterpret_cast<const float4*>(w)[i];
  ushort4 o;
  o.x = f2bf(v.x); o.y = f2bf(v.y); o.z = f2bf(v.z); o.w = f2bf(v.w);
  reinterpret_cast<ushort4*>(wb)[i] = o;
}

// ---------------- K1: stream row -> LDS, gather + softmax -> P (bf16) ----------------
// One block per (b,i). Streams M[sid][0..8192] coalesced (32 dwords/lane, deep MLP;
// scalar dwords deliberate: row stride 32772B is only 4B-aligned), then gathers the
// 1024 needed columns from LDS. Masked (id<=0) entries: score 0 -> exp 1.
__global__ __launch_bounds__(256) void gather_softmax(const int* __restrict__ ids,
                                                      const float* __restrict__ Mx,
                                                      unsigned short* __restrict__ P) {
  __shared__ float row[kV];   // 32772 B
  __shared__ float red[4];
  const int i = blockIdx.x, b = blockIdx.y;
  const int t = threadIdx.x;
  const int sid = ids[b * kS + i];          // block-uniform
  if (sid > 0) {
    const float* src = Mx + (long)sid * kV;
#pragma unroll
    for (int q = 0; q < 32; ++q) row[t + q * 256] = src[t + q * 256];
    if (t == 0) row[8192] = src[8192];
  }
  __syncthreads();
  const int4 cj4 = reinterpret_cast<const int4*>(ids + b * kS)[t]; // 4 consecutive j
  const int cj[4] = {cj4.x, cj4.y, cj4.z, cj4.w};
  const float scale = 0.036084391824351615f; // 1/sqrt(768)
  float e[4];
  float lsum = 0.f;
#pragma unroll
  for (int q = 0; q < 4; ++q) {
    float v = 1.0f;                          // masked => score 0 => exp = 1
    if (sid > 0 && cj[q] > 0) v = __expf(row[cj[q]] * scale);
    e[q] = v; lsum += v;
  }
#pragma unroll
  for (int o = 32; o; o >>= 1) lsum += __shfl_down(lsum, o);
  if ((t & 63) == 0) red[t >> 6] = lsum;
  __syncthreads();
  const float denom = red[0] + red[1] + red[2] + red[3];
  const float inv = 1.0f / denom;
  ushort4 o;
  o.x = f2bf(e[0] * inv); o.y = f2bf(e[1] * inv);
  o.z = f2bf(e[2] * inv); o.w = f2bf(e[3] * inv);
  reinterpret_cast<ushort4*>(P + ((long)b * kS + i) * kS)[t] = o;
}

// ---------------- K2: hidden -> hT (bf16, [B][H][S]) ----------------
__global__ __launch_bounds__(256) void transpose_h(const float* __restrict__ hidden,
                                                   unsigned short* __restrict__ hT) {
  __shared__ float tile[32][33];
  const int b = blockIdx.z;
  const int h0 = blockIdx.x * 32;  // H dim
  const int s0 = blockIdx.y * 32;  // S dim
  const int t = threadIdx.x;
  const int c = t & 31, r0 = t >> 5;
  const float* src = hidden + (long)b * kS * kH;
#pragma unroll
  for (int q = 0; q < 4; ++q) {
    int r = r0 + q * 8;
    tile[r][c] = src[(long)(s0 + r) * kH + h0 + c];
  }
  __syncthreads();
  unsigned short* dst = hT + (long)b * kH * kS;
#pragma unroll
  for (int q = 0; q < 4; ++q) {
    int hh = r0 + q * 8;
    dst[(long)(h0 + hh) * kS + s0 + c] = f2bf(tile[c][hh]);
  }
}

// ---------------- K3/K4: m97-structure NT GEMM ----------------
// C[m,n] = sum_k A[m,k] * Bt[n,k]; 128x128 block tile, BK=32, 4 waves each 64x64,
// 16 MFMA (16x16x32 bf16) per wave per K-step. Linear LDS + global_load_lds x16B
// (2-phase schedule: per regime gate, no swizzle — barrier drain dominates anyway).
template <int OUT_BF16>
__global__ __launch_bounds__(256) void gemm_nt(
    const unsigned short* __restrict__ A, long aStride,
    const unsigned short* __restrict__ Bt, long bStride,
    void* __restrict__ C, long cStride, int N, int K) {
  __shared__ __align__(1024) unsigned short lds[8192]; // A:[0,4096) B:[4096,8192) elems (16KB)
  const int b = blockIdx.z, bn = blockIdx.x, bm = blockIdx.y;
  const unsigned short* Ab = A + (long)b * aStride + (long)(bm * 128) * K;
  const unsigned short* Bb = Bt + (long)b * bStride + (long)(bn * 128) * K;
  const int t = threadIdx.x;
  const int lane = t & 63;
  const int wr = (t >> 7) & 1, wc = (t >> 6) & 1;  // wave -> 64x64 quadrant
  const int lrow = lane & 15, kq = lane >> 4;
  // staging: issue q in {0,1}: element = t*8 + q*2048 -> row t/4 + q*64, col (t&3)*8
  const int srow = t >> 2, scol = (t & 3) * 8;
  char* ldsb = (char*)lds;

  f32x4 acc[4][4];
#pragma unroll
  for (int mi = 0; mi < 4; ++mi)
#pragma unroll
    for (int ni = 0; ni < 4; ++ni) acc[mi][ni] = (f32x4){0.f, 0.f, 0.f, 0.f};

  for (int kt = 0; kt < K; kt += 32) {
#pragma unroll
    for (int q = 0; q < 2; ++q) {
      async_lds16(Ab + (long)(srow + q * 64) * K + kt + scol, ldsb + t * 16 + q * 4096);
      async_lds16(Bb + (long)(srow + q * 64) * K + kt + scol, ldsb + 8192 + t * 16 + q * 4096);
    }
    __syncthreads();                        // compiler drains vmcnt before barrier
    short8 af[4], bf[4];
#pragma unroll
    for (int mi = 0; mi < 4; ++mi)
      af[mi] = *reinterpret_cast<const short8*>(&lds[(wr * 64 + mi * 16 + lrow) * 32 + kq * 8]);
#pragma unroll
    for (int ni = 0; ni < 4; ++ni)
      bf[ni] = *reinterpret_cast<const short8*>(&lds[4096 + (wc * 64 + ni * 16 + lrow) * 32 + kq * 8]);
#pragma unroll
    for (int mi = 0; mi < 4; ++mi)
#pragma unroll
      for (int ni = 0; ni < 4; ++ni)
        acc[mi][ni] = __builtin_amdgcn_mfma_f32_16x16x32_bf16(af[mi], bf[ni], acc[mi][ni], 0, 0, 0);
    __syncthreads();
  }

  // C/D layout: col = lane&15, row = (lane>>4)*4 + reg (m89/m91 verified)
  const int row0 = bm * 128 + wr * 64;
  const int col0 = bn * 128 + wc * 64;
#pragma unroll
  for (int mi = 0; mi < 4; ++mi)
#pragma unroll
    for (int ni = 0; ni < 4; ++ni)
#pragma unroll
      for (int rg = 0; rg < 4; ++rg) {
        int r = row0 + mi * 16 + kq * 4 + rg;
        int c = col0 + ni * 16 + lrow;
        long off = (long)b * cStride + (long)r * N + c;
        float v = acc[mi][ni][rg];
        if (OUT_BF16) ((unsigned short*)C)[off] = f2bf(v);
        else ((float*)C)[off] = v;
      }
}

// ---------------- K5: out = LN(hidden + proj + out_b), float4 ----------------
__global__ __launch_bounds__(192) void residual_ln(
    const float* __restrict__ hidden, const float* __restrict__ proj,
    const float* __restrict__ ob, const float* __restrict__ lw,
    const float* __restrict__ lb, float* __restrict__ out) {
  const long row = blockIdx.x;
  const int t = threadIdx.x;                  // 192 threads * float4 = 768
  float4 hv = reinterpret_cast<const float4*>(hidden + row * kH)[t];
  float4 pv = reinterpret_cast<const float4*>(proj + row * kH)[t];
  float4 bv = reinterpret_cast<const float4*>(ob)[t];
  float4 x;
  x.x = hv.x + pv.x + bv.x; x.y = hv.y + pv.y + bv.y;
  x.z = hv.z + pv.z + bv.z; x.w = hv.w + pv.w + bv.w;
  float s = x.x + x.y + x.z + x.w;
  float sq = x.x * x.x + x.y * x.y + x.z * x.z + x.w * x.w;
#pragma unroll
  for (int o = 32; o; o >>= 1) { s += __shfl_down(s, o); sq += __shfl_down(sq, o); }
  __shared__ float rs[3], rq[3];
  if ((t & 63) == 0) { rs[t >> 6] = s; rq[t >> 6] = sq; }
  __syncthreads();
  const float ts = rs[0] + rs[1] + rs[2];
  const float tq = rq[0] + rq[1] + rq[2];
  const float invH = 1.0f / 768.0f;
  const float mu = ts * invH;
  const float var = tq * invH - mu * mu;
  const float rstd = rsqrtf(var + 1e-5f);
  float4 wv = reinterpret_cast<const float4*>(lw)[t];
  float4 lv = reinterpret_cast<const float4*>(lb)[t];
  float4 o4;
  o4.x = (x.x - mu) * rstd * wv.x + lv.x;
  o4.y = (x.y - mu) * rstd * wv.y + lv.y;
  o4.z = (x.z - mu) * rstd * wv.z + lv.z;
  o4.w = (x.w - mu) * rstd * wv.w + lv.w;
  reinterpret_cast<float4*>(out + row * kH)[t] = o4;
}

extern "C" void kernel_launch(void* const* d_in, const int* in_sizes, int n_in,
                              void* d_out, int out_size, void* d_ws, size_t ws_size,
                              hipStream_t stream) {
  const float* hidden = (const float*)d_in[0];
  const int* ids      = (const int*)d_in[1];
  const float* Mx     = (const float*)d_in[2];
  const float* out_w  = (const float*)d_in[3];
  const float* out_b  = (const float*)d_in[4];
  const float* ln_w   = (const float*)d_in[5];
  const float* ln_b   = (const float*)d_in[6];
  float* out = (float*)d_out;

  // Workspace: P bf16 [0,16.78M) | hT bf16 [16.78M,29.36M) | ctx bf16 [29.36M,41.94M)
  //            Wb bf16 [41.94M,43.12M) | proj fp32 reuses [0,25.17M) after K3.
  char* ws = (char*)d_ws;
  const long szP = 16777216L, szHT = 12582912L, szCTX = 12582912L;
  unsigned short* P   = (unsigned short*)ws;
  unsigned short* hT  = (unsigned short*)(ws + szP);
  unsigned short* ctx = (unsigned short*)(ws + szP + szHT);
  unsigned short* Wb  = (unsigned short*)(ws + szP + szHT + szCTX);
  float* proj = (float*)ws;

  convert_w<<<576, 256, 0, stream>>>(out_w, Wb);
  gather_softmax<<<dim3(1024, 8), 256, 0, stream>>>(ids, Mx, P);
  transpose_h<<<dim3(24, 32, 8), 256, 0, stream>>>(hidden, hT);
  // ctx[b,i,d] = sum_j P[b,i,j] * hT[b,d,j]
  gemm_nt<1><<<dim3(6, 8, 8), 256, 0, stream>>>(
      P, (long)kS * kS, hT, (long)kH * kS, ctx, (long)kS * kH, kH, kS);
  // proj[b,i,o] = sum_d ctx[b,i,d] * Wb[o,d]
  gemm_nt<0><<<dim3(6, 8, 8), 256, 0, stream>>>(
      ctx, (long)kS * kH, Wb, 0L, proj, (long)kS * kH, kH, kH);
  residual_ln<<<8192, 192, 0, stream>>>(hidden, proj, out_b, ln_w, ln_b, out);
}